// Round 1
// baseline (1707.520 us; speedup 1.0000x reference)
//
#include <hip/hip_runtime.h>

// ---------------------------------------------------------------------------
// Qwen2 attention forward: QKV proj + RoPE + causal GQA attention + O proj
// B=2 S=2048 HIDDEN=3584 NH=28 NKV=4 D=128
// ---------------------------------------------------------------------------

typedef __bf16 bf16x8 __attribute__((ext_vector_type(8)));
typedef float floatx4 __attribute__((ext_vector_type(4)));
typedef unsigned short ushort8v __attribute__((ext_vector_type(8)));
typedef unsigned short ushort4v __attribute__((ext_vector_type(4)));

__device__ __forceinline__ unsigned short f2bf(float f) {
    union { float f; unsigned int u; } v; v.f = f;
    return (unsigned short)((v.u + 0x7fffu + ((v.u >> 16) & 1u)) >> 16);
}
__device__ __forceinline__ float bf2f(unsigned short b) {
    union { unsigned int u; float f; } v; v.u = ((unsigned int)b) << 16;
    return v.f;
}
__device__ __forceinline__ floatx4 mfma16(bf16x8 a, bf16x8 b, floatx4 c) {
    return __builtin_amdgcn_mfma_f32_16x16x32_bf16(a, b, c, 0, 0, 0);
}
__device__ __forceinline__ bf16x8 lds_frag(const unsigned short* p) {
    ushort8v t = *(const ushort8v*)p;
    return __builtin_bit_cast(bf16x8, t);
}

// ---------------------------------------------------------------------------
// NT GEMM: C[m][n] = sum_k A[m][k] * B[n][k]  (+ bias[n])
// A: fp32 or bf16-bits row-major (lda=K); B: fp32 row-major (ldb=K)
// 128x128 tile, BK=32, 256 threads (4 waves, 2x2 of 64x64 each = 4x4 frags)
// ---------------------------------------------------------------------------
template<bool A_BF16, bool HAS_BIAS, bool OUT_BF16>
__global__ __launch_bounds__(256) void gemm_nt(
    const void* __restrict__ Ap, const float* __restrict__ Bp,
    const float* __restrict__ bias, void* __restrict__ Cp,
    int M, int N, int K, int ldc)
{
    __shared__ unsigned short As[128][40];   // +8 pad: 2-way-max bank aliasing
    __shared__ unsigned short Bs[128][40];

    const int tid  = threadIdx.x;
    const int lane = tid & 63;
    const int w    = tid >> 6;
    const int quad = lane >> 4;
    const int l16  = lane & 15;
    const int m0 = blockIdx.x * 128, n0 = blockIdx.y * 128;
    const int wm = (w & 1) * 64, wn = (w >> 1) * 64;

    floatx4 acc[4][4] = {};

    for (int k0 = 0; k0 < K; k0 += 32) {
        __syncthreads();
        // ---- stage A tile (128 x 32) ----
        if (A_BF16) {
            const unsigned short* Ab = (const unsigned short*)Ap;
            #pragma unroll
            for (int p = 0; p < 2; ++p) {
                int idx = tid + p * 256;
                int row = idx >> 2, seg = idx & 3;
                ushort8v v = *(const ushort8v*)(Ab + (size_t)(m0 + row) * K + k0 + seg * 8);
                *(ushort8v*)&As[row][seg * 8] = v;
            }
        } else {
            const float* Af = (const float*)Ap;
            #pragma unroll
            for (int p = 0; p < 4; ++p) {
                int idx = tid + p * 256;
                int row = idx >> 3, seg = idx & 7;
                const float4 v = *(const float4*)(Af + (size_t)(m0 + row) * K + k0 + seg * 4);
                ushort4v b;
                b[0] = f2bf(v.x); b[1] = f2bf(v.y); b[2] = f2bf(v.z); b[3] = f2bf(v.w);
                *(ushort4v*)&As[row][seg * 4] = b;
            }
        }
        // ---- stage B tile (128 x 32), fp32 weights ----
        {
            #pragma unroll
            for (int p = 0; p < 4; ++p) {
                int idx = tid + p * 256;
                int row = idx >> 3, seg = idx & 7;
                const float4 v = *(const float4*)(Bp + (size_t)(n0 + row) * K + k0 + seg * 4);
                ushort4v b;
                b[0] = f2bf(v.x); b[1] = f2bf(v.y); b[2] = f2bf(v.z); b[3] = f2bf(v.w);
                *(ushort4v*)&Bs[row][seg * 4] = b;
            }
        }
        __syncthreads();
        // ---- 16 MFMAs ----
        bf16x8 af[4], bv[4];
        #pragma unroll
        for (int i = 0; i < 4; ++i) af[i] = lds_frag(&As[wm + i * 16 + l16][quad * 8]);
        #pragma unroll
        for (int j = 0; j < 4; ++j) bv[j] = lds_frag(&Bs[wn + j * 16 + l16][quad * 8]);
        #pragma unroll
        for (int i = 0; i < 4; ++i)
            #pragma unroll
            for (int j = 0; j < 4; ++j)
                acc[i][j] = mfma16(af[i], bv[j], acc[i][j]);
    }

    // ---- epilogue: C row = quad*4+r, col = l16 ----
    #pragma unroll
    for (int j = 0; j < 4; ++j) {
        int col = n0 + wn + j * 16 + l16;
        float bb = HAS_BIAS ? bias[col] : 0.0f;
        #pragma unroll
        for (int i = 0; i < 4; ++i) {
            int row = m0 + wm + i * 16 + quad * 4;
            #pragma unroll
            for (int r = 0; r < 4; ++r) {
                float v = acc[i][j][r] + bb;
                if (OUT_BF16)
                    ((unsigned short*)Cp)[(size_t)(row + r) * ldc + col] = f2bf(v);
                else
                    ((float*)Cp)[(size_t)(row + r) * ldc + col] = v;
            }
        }
    }
}

// ---------------------------------------------------------------------------
// RoPE in place on bf16 q (28 heads) and k (4 heads).
// grid (4096 tokens, 32 "heads": 0..27 -> q, 28..31 -> k), block 128.
// ---------------------------------------------------------------------------
__global__ __launch_bounds__(128) void rope_kernel(
    unsigned short* __restrict__ Q, unsigned short* __restrict__ K,
    const float* __restrict__ cosp, const float* __restrict__ sinp)
{
    const int tok = blockIdx.x;
    const int hh  = blockIdx.y;
    const int d   = threadIdx.x;
    unsigned short* base = (hh < 28)
        ? Q + (size_t)tok * 3584 + hh * 128
        : K + (size_t)tok * 512 + (hh - 28) * 128;
    __shared__ float xs[128];
    float x = bf2f(base[d]);
    xs[d] = x;
    __syncthreads();
    float rot = (d < 64) ? -xs[d + 64] : xs[d - 64];
    float c = cosp[(size_t)tok * 128 + d];
    float s = sinp[(size_t)tok * 128 + d];
    base[d] = f2bf(x * c + rot * s);
}

// ---------------------------------------------------------------------------
// Flash attention, causal, GQA 7:1.
// Block = (q-tile of 64 rows, head, batch); 256 threads = 4 waves x 16 rows.
// ---------------------------------------------------------------------------
__global__ __launch_bounds__(256) void attn_kernel(
    const unsigned short* __restrict__ Q, const unsigned short* __restrict__ Kb,
    const unsigned short* __restrict__ Vb, unsigned short* __restrict__ O)
{
    const int qt = blockIdx.x;   // 0..31
    const int h  = blockIdx.y;   // 0..27
    const int b  = blockIdx.z;   // 0..1
    const int kvh = h / 7;
    const int tid = threadIdx.x;
    const int lane = tid & 63, w = tid >> 6;
    const int quad = lane >> 4, l16 = lane & 15;

    __shared__ unsigned short Qs[64][136];    // [qrow][d]
    __shared__ unsigned short Ks[64][136];    // [key][d]
    __shared__ unsigned short VsT[128][72];   // [d][key]
    __shared__ unsigned short Ps[64][72];     // [qrow][key]

    // stage Q tile once
    #pragma unroll
    for (int p = 0; p < 4; ++p) {
        int idx = tid + p * 256;
        int row = idx >> 4, seg = idx & 15;
        ushort8v v = *(const ushort8v*)(Q + (size_t)(b * 2048 + qt * 64 + row) * 3584 + h * 128 + seg * 8);
        *(ushort8v*)&Qs[row][seg * 8] = v;
    }

    floatx4 o[8] = {};
    float mrow[4] = {-1e30f, -1e30f, -1e30f, -1e30f};
    float lrow[4] = {0.f, 0.f, 0.f, 0.f};
    const float scaling = 0.08838834764831845f;  // 1/sqrt(128)

    for (int kt = 0; kt <= qt; ++kt) {
        __syncthreads();   // protect Ks/VsT from previous iteration's readers
        // ---- stage K tile ----
        #pragma unroll
        for (int p = 0; p < 4; ++p) {
            int idx = tid + p * 256;
            int row = idx >> 4, seg = idx & 15;
            ushort8v v = *(const ushort8v*)(Kb + (size_t)(b * 2048 + kt * 64 + row) * 512 + kvh * 128 + seg * 8);
            *(ushort8v*)&Ks[row][seg * 8] = v;
        }
        // ---- stage V tile transposed (lane-rotated to break bank conflicts) ----
        #pragma unroll
        for (int p = 0; p < 4; ++p) {
            int idx = tid + p * 256;
            int key = idx >> 4, seg = idx & 15;
            ushort8v v = *(const ushort8v*)(Vb + (size_t)(b * 2048 + kt * 64 + key) * 512 + kvh * 128 + seg * 8);
            #pragma unroll
            for (int ee = 0; ee < 8; ++ee) {
                int e = (ee + lane) & 7;
                VsT[seg * 8 + e][key] = v[e];
            }
        }
        __syncthreads();

        // ---- S = Q K^T : wave's 16 rows x 64 keys ----
        floatx4 s[4] = {};
        #pragma unroll
        for (int ks = 0; ks < 4; ++ks) {
            bf16x8 aq = lds_frag(&Qs[w * 16 + l16][ks * 32 + quad * 8]);
            #pragma unroll
            for (int n4 = 0; n4 < 4; ++n4) {
                bf16x8 bk = lds_frag(&Ks[n4 * 16 + l16][ks * 32 + quad * 8]);
                s[n4] = mfma16(aq, bk, s[n4]);
            }
        }

        // ---- online softmax (rows owned per-quad; butterfly over 16 lanes) ----
        const bool diag = (kt == qt);
        float pv[4][4];
        #pragma unroll
        for (int r = 0; r < 4; ++r) {
            int qg = qt * 64 + w * 16 + quad * 4 + r;
            float v0 = s[0][r] * scaling;
            float v1 = s[1][r] * scaling;
            float v2 = s[2][r] * scaling;
            float v3 = s[3][r] * scaling;
            if (diag) {
                int kg = kt * 64 + l16;
                if (kg      > qg) v0 = -1e30f;
                if (kg + 16 > qg) v1 = -1e30f;
                if (kg + 32 > qg) v2 = -1e30f;
                if (kg + 48 > qg) v3 = -1e30f;
            }
            float mx = fmaxf(fmaxf(v0, v1), fmaxf(v2, v3));
            #pragma unroll
            for (int off = 1; off < 16; off <<= 1)
                mx = fmaxf(mx, __shfl_xor(mx, off, 64));
            float mnew  = fmaxf(mrow[r], mx);
            float alpha = __expf(mrow[r] - mnew);
            float p0 = __expf(v0 - mnew);
            float p1 = __expf(v1 - mnew);
            float p2 = __expf(v2 - mnew);
            float p3 = __expf(v3 - mnew);
            float rs = p0 + p1 + p2 + p3;
            #pragma unroll
            for (int off = 1; off < 16; off <<= 1)
                rs += __shfl_xor(rs, off, 64);
            lrow[r] = lrow[r] * alpha + rs;
            mrow[r] = mnew;
            #pragma unroll
            for (int d4 = 0; d4 < 8; ++d4) o[d4][r] *= alpha;
            pv[r][0] = p0; pv[r][1] = p1; pv[r][2] = p2; pv[r][3] = p3;
        }

        // ---- P -> LDS (C-layout write); read back in A-layout (same wave only) ----
        #pragma unroll
        for (int n4 = 0; n4 < 4; ++n4)
            #pragma unroll
            for (int r = 0; r < 4; ++r)
                Ps[w * 16 + quad * 4 + r][n4 * 16 + l16] = f2bf(pv[r][n4]);

        // ---- O += P V ----
        #pragma unroll
        for (int ks = 0; ks < 2; ++ks) {
            bf16x8 ap = lds_frag(&Ps[w * 16 + l16][ks * 32 + quad * 8]);
            #pragma unroll
            for (int d4 = 0; d4 < 8; ++d4) {
                bf16x8 bv = lds_frag(&VsT[d4 * 16 + l16][ks * 32 + quad * 8]);
                o[d4] = mfma16(ap, bv, o[d4]);
            }
        }
    }

    // ---- epilogue: O /= l, write bf16 ----
    #pragma unroll
    for (int d4 = 0; d4 < 8; ++d4) {
        int col = h * 128 + d4 * 16 + l16;
        #pragma unroll
        for (int r = 0; r < 4; ++r) {
            int row = b * 2048 + qt * 64 + w * 16 + quad * 4 + r;
            O[(size_t)row * 3584 + col] = f2bf(o[d4][r] / lrow[r]);
        }
    }
}

// ---------------------------------------------------------------------------
extern "C" void kernel_launch(void* const* d_in, const int* in_sizes, int n_in,
                              void* d_out, int out_size, void* d_ws, size_t ws_size,
                              hipStream_t stream)
{
    (void)in_sizes; (void)n_in; (void)out_size; (void)ws_size;
    const float* hs   = (const float*)d_in[0];
    const float* cosp = (const float*)d_in[1];
    const float* sinp = (const float*)d_in[2];
    const float* Wq   = (const float*)d_in[3];
    const float* bq   = (const float*)d_in[4];
    const float* Wk   = (const float*)d_in[5];
    const float* bk   = (const float*)d_in[6];
    const float* Wv   = (const float*)d_in[7];
    const float* bv   = (const float*)d_in[8];
    const float* Wo   = (const float*)d_in[9];
    float* out = (float*)d_out;

    unsigned short* qb = (unsigned short*)d_ws;           // 4096*3584 bf16
    unsigned short* kb = qb + (size_t)4096 * 3584;        // 4096*512
    unsigned short* vb = kb + (size_t)4096 * 512;         // 4096*512
    unsigned short* ab = vb + (size_t)4096 * 512;         // 4096*3584

    dim3 blk(256);
    gemm_nt<false, true, true><<<dim3(32, 28), blk, 0, stream>>>(hs, Wq, bq, qb, 4096, 3584, 3584, 3584);
    gemm_nt<false, true, true><<<dim3(32, 4),  blk, 0, stream>>>(hs, Wk, bk, kb, 4096, 512, 3584, 512);
    gemm_nt<false, true, true><<<dim3(32, 4),  blk, 0, stream>>>(hs, Wv, bv, vb, 4096, 512, 3584, 512);
    rope_kernel<<<dim3(4096, 32), dim3(128), 0, stream>>>(qb, kb, cosp, sinp);
    attn_kernel<<<dim3(32, 28, 2), blk, 0, stream>>>(qb, kb, vb, ab);
    gemm_nt<true, false, false><<<dim3(32, 28), blk, 0, stream>>>(ab, Wo, nullptr, out, 4096, 3584, 3584, 3584);
}

// Round 2
// 1216.127 us; speedup vs baseline: 1.4041x; 1.4041x over previous
//
#include <hip/hip_runtime.h>

// ---------------------------------------------------------------------------
// Qwen2 attention forward: QKV proj + RoPE + causal GQA attention + O proj
// B=2 S=2048 HIDDEN=3584 NH=28 NKV=4 D=128
// ---------------------------------------------------------------------------

typedef __bf16 bf16x8 __attribute__((ext_vector_type(8)));
typedef float floatx4 __attribute__((ext_vector_type(4)));
typedef unsigned short ushort8v __attribute__((ext_vector_type(8)));
typedef unsigned short ushort4v __attribute__((ext_vector_type(4)));

__device__ __forceinline__ unsigned short f2bf(float f) {
    union { float f; unsigned int u; } v; v.f = f;
    return (unsigned short)((v.u + 0x7fffu + ((v.u >> 16) & 1u)) >> 16);
}
__device__ __forceinline__ float bf2f(unsigned short b) {
    union { unsigned int u; float f; } v; v.u = ((unsigned int)b) << 16;
    return v.f;
}
__device__ __forceinline__ floatx4 mfma16(bf16x8 a, bf16x8 b, floatx4 c) {
    return __builtin_amdgcn_mfma_f32_16x16x32_bf16(a, b, c, 0, 0, 0);
}
__device__ __forceinline__ bf16x8 ld8(const unsigned short* p) {
    ushort8v t = *(const ushort8v*)p;
    return __builtin_bit_cast(bf16x8, t);
}

// async global->LDS, 16B per lane; LDS dest = wave-uniform base + lane*16
#define GLL16(g, l) __builtin_amdgcn_global_load_lds( \
    (const __attribute__((address_space(1))) void*)(g), \
    (__attribute__((address_space(3))) void*)(l), 16, 0, 0)

// ---------------------------------------------------------------------------
// fp32 -> bf16 bulk convert of 5 arrays (vec4 granularity)
// ---------------------------------------------------------------------------
__global__ __launch_bounds__(256) void convert5(
    const float* __restrict__ s0, const float* __restrict__ s1,
    const float* __restrict__ s2, const float* __restrict__ s3,
    const float* __restrict__ s4,
    unsigned short* __restrict__ d0, unsigned short* __restrict__ d1,
    unsigned short* __restrict__ d2, unsigned short* __restrict__ d3,
    unsigned short* __restrict__ d4,
    int n0, int n1, int n2, int n3, int n4)
{
    int total = n0 + n1 + n2 + n3 + n4;
    for (int i = blockIdx.x * blockDim.x + threadIdx.x; i < total;
         i += gridDim.x * blockDim.x) {
        const float* s; unsigned short* d; int j = i;
        if (j < n0)      { s = s0; d = d0; }
        else { j -= n0; if (j < n1) { s = s1; d = d1; }
        else { j -= n1; if (j < n2) { s = s2; d = d2; }
        else { j -= n2; if (j < n3) { s = s3; d = d3; }
        else { j -= n3;   s = s4; d = d4; } } } }
        float4 v = ((const float4*)s)[j];
        ushort4v o;
        o[0] = f2bf(v.x); o[1] = f2bf(v.y); o[2] = f2bf(v.z); o[3] = f2bf(v.w);
        ((ushort4v*)d)[j] = o;
    }
}

// ---------------------------------------------------------------------------
// all-bf16 NT GEMM: C[m][n] = sum_k A[m][k]*B[n][k] (+bias[n])
// 128x128 tile, BK=32, global_load_lds staging into XOR-swizzled LDS.
// ---------------------------------------------------------------------------
template<bool HAS_BIAS, bool OUT_BF16>
__global__ __launch_bounds__(256) void gemm_bb(
    const unsigned short* __restrict__ A, const unsigned short* __restrict__ B,
    const float* __restrict__ bias, void* __restrict__ C,
    int K, int ldc)
{
    __shared__ unsigned short As[128 * 32];   // row stride 32 ushorts, swizzled
    __shared__ unsigned short Bs[128 * 32];

    const int tid = threadIdx.x, lane = tid & 63, w = tid >> 6;
    const int quad = lane >> 4, l16 = lane & 15;
    const int m0 = blockIdx.x * 128, n0 = blockIdx.y * 128;
    const int wm = (w & 1) * 64, wn = (w >> 1) * 64;

    floatx4 acc[4][4] = {};

    for (int k0 = 0; k0 < K; k0 += 32) {
        __syncthreads();
        #pragma unroll
        for (int p = 0; p < 2; ++p) {
            int c = (w * 2 + p) * 64 + lane;      // chunk 0..511
            int row = c >> 2, sp = c & 3;
            int slog = sp ^ ((row ^ (row >> 2)) & 3);
            GLL16(A + (size_t)(m0 + row) * K + k0 + slog * 8,
                  (unsigned short*)As + (w * 2 + p) * 512);
            GLL16(B + (size_t)(n0 + row) * K + k0 + slog * 8,
                  (unsigned short*)Bs + (w * 2 + p) * 512);
        }
        __syncthreads();
        bf16x8 af[4], bf[4];
        #pragma unroll
        for (int i = 0; i < 4; ++i) {
            int row = wm + i * 16 + l16;
            int sp = quad ^ ((row ^ (row >> 2)) & 3);
            af[i] = ld8((unsigned short*)As + row * 32 + sp * 8);
        }
        #pragma unroll
        for (int j = 0; j < 4; ++j) {
            int row = wn + j * 16 + l16;
            int sp = quad ^ ((row ^ (row >> 2)) & 3);
            bf[j] = ld8((unsigned short*)Bs + row * 32 + sp * 8);
        }
        #pragma unroll
        for (int i = 0; i < 4; ++i)
            #pragma unroll
            for (int j = 0; j < 4; ++j)
                acc[i][j] = mfma16(af[i], bf[j], acc[i][j]);
    }

    #pragma unroll
    for (int j = 0; j < 4; ++j) {
        int col = n0 + wn + j * 16 + l16;
        float bb = HAS_BIAS ? bias[col] : 0.0f;
        #pragma unroll
        for (int i = 0; i < 4; ++i) {
            int row = m0 + wm + i * 16 + quad * 4;
            #pragma unroll
            for (int r = 0; r < 4; ++r) {
                float v = acc[i][j][r] + bb;
                if (OUT_BF16)
                    ((unsigned short*)C)[(size_t)(row + r) * ldc + col] = f2bf(v);
                else
                    ((float*)C)[(size_t)(row + r) * ldc + col] = v;
            }
        }
    }
}

// ---------------------------------------------------------------------------
// v1 fp32-staging GEMM (fallback path when workspace is small)
// ---------------------------------------------------------------------------
template<bool A_BF16, bool HAS_BIAS, bool OUT_BF16>
__global__ __launch_bounds__(256) void gemm_nt(
    const void* __restrict__ Ap, const float* __restrict__ Bp,
    const float* __restrict__ bias, void* __restrict__ Cp,
    int K, int ldc)
{
    __shared__ unsigned short As[128][40];
    __shared__ unsigned short Bs[128][40];

    const int tid = threadIdx.x, lane = tid & 63, w = tid >> 6;
    const int quad = lane >> 4, l16 = lane & 15;
    const int m0 = blockIdx.x * 128, n0 = blockIdx.y * 128;
    const int wm = (w & 1) * 64, wn = (w >> 1) * 64;

    floatx4 acc[4][4] = {};

    for (int k0 = 0; k0 < K; k0 += 32) {
        __syncthreads();
        if (A_BF16) {
            const unsigned short* Ab = (const unsigned short*)Ap;
            #pragma unroll
            for (int p = 0; p < 2; ++p) {
                int idx = tid + p * 256;
                int row = idx >> 2, seg = idx & 3;
                ushort8v v = *(const ushort8v*)(Ab + (size_t)(m0 + row) * K + k0 + seg * 8);
                *(ushort8v*)&As[row][seg * 8] = v;
            }
        } else {
            const float* Af = (const float*)Ap;
            #pragma unroll
            for (int p = 0; p < 4; ++p) {
                int idx = tid + p * 256;
                int row = idx >> 3, seg = idx & 7;
                const float4 v = *(const float4*)(Af + (size_t)(m0 + row) * K + k0 + seg * 4);
                ushort4v b;
                b[0] = f2bf(v.x); b[1] = f2bf(v.y); b[2] = f2bf(v.z); b[3] = f2bf(v.w);
                *(ushort4v*)&As[row][seg * 4] = b;
            }
        }
        #pragma unroll
        for (int p = 0; p < 4; ++p) {
            int idx = tid + p * 256;
            int row = idx >> 3, seg = idx & 7;
            const float4 v = *(const float4*)(Bp + (size_t)(n0 + row) * K + k0 + seg * 4);
            ushort4v b;
            b[0] = f2bf(v.x); b[1] = f2bf(v.y); b[2] = f2bf(v.z); b[3] = f2bf(v.w);
            *(ushort4v*)&Bs[row][seg * 4] = b;
        }
        __syncthreads();
        bf16x8 af[4], bv[4];
        #pragma unroll
        for (int i = 0; i < 4; ++i) af[i] = ld8(&As[wm + i * 16 + l16][quad * 8]);
        #pragma unroll
        for (int j = 0; j < 4; ++j) bv[j] = ld8(&Bs[wn + j * 16 + l16][quad * 8]);
        #pragma unroll
        for (int i = 0; i < 4; ++i)
            #pragma unroll
            for (int j = 0; j < 4; ++j)
                acc[i][j] = mfma16(af[i], bv[j], acc[i][j]);
    }

    #pragma unroll
    for (int j = 0; j < 4; ++j) {
        int col = n0 + wn + j * 16 + l16;
        float bb = HAS_BIAS ? bias[col] : 0.0f;
        #pragma unroll
        for (int i = 0; i < 4; ++i) {
            int row = m0 + wm + i * 16 + quad * 4;
            #pragma unroll
            for (int r = 0; r < 4; ++r) {
                float v = acc[i][j][r] + bb;
                if (OUT_BF16)
                    ((unsigned short*)Cp)[(size_t)(row + r) * ldc + col] = f2bf(v);
                else
                    ((float*)Cp)[(size_t)(row + r) * ldc + col] = v;
            }
        }
    }
}

// ---------------------------------------------------------------------------
// RoPE in place: one block per token, 32 head-slices (28 q + 4 k)
// ---------------------------------------------------------------------------
__global__ __launch_bounds__(256) void rope2(
    unsigned short* __restrict__ Q, unsigned short* __restrict__ K,
    const float* __restrict__ cosp, const float* __restrict__ sinp)
{
    const int tok = blockIdx.x, tid = threadIdx.x;
    __shared__ float cs[128], ss[128];
    if (tid < 128) {
        cs[tid] = cosp[(size_t)tok * 128 + tid];
        ss[tid] = sinp[(size_t)tok * 128 + tid];
    }
    __syncthreads();

    ushort8v x[2], x2[2];
    unsigned short* bases[2];
    int segs[2];
    #pragma unroll
    for (int p = 0; p < 2; ++p) {
        int chunk = tid + p * 256;              // 0..511
        int hh = chunk >> 4, seg = chunk & 15;
        unsigned short* base = (hh < 28)
            ? Q + (size_t)tok * 3584 + hh * 128
            : K + (size_t)tok * 512 + (hh - 28) * 128;
        bases[p] = base; segs[p] = seg;
        x[p]  = *(const ushort8v*)(base + seg * 8);
        x2[p] = *(const ushort8v*)(base + (seg ^ 8) * 8);
    }
    __syncthreads();   // all reads complete before any thread writes
    #pragma unroll
    for (int p = 0; p < 2; ++p) {
        int seg = segs[p];
        ushort8v y;
        #pragma unroll
        for (int j = 0; j < 8; ++j) {
            int d = seg * 8 + j;
            float xv = bf2f(x[p][j]);
            float rv = bf2f(x2[p][j]);
            float rot = (seg < 8) ? -rv : rv;
            y[j] = f2bf(xv * cs[d] + rot * ss[d]);
        }
        *(ushort8v*)(bases[p] + seg * 8) = y;
    }
}

// ---------------------------------------------------------------------------
// V transpose: vb[4096 tok][512 gd] -> vt[512 gd][4096 tok]
// ---------------------------------------------------------------------------
__global__ __launch_bounds__(256) void transpose_v(
    const unsigned short* __restrict__ vb, unsigned short* __restrict__ vt)
{
    __shared__ unsigned short Ts[64][68];
    const int t0 = blockIdx.x * 64, c0 = blockIdx.y * 64;
    const int tid = threadIdx.x;
    #pragma unroll
    for (int it = 0; it < 4; ++it) {
        int idx = tid + it * 256;
        int row = idx >> 4, seg = idx & 15;
        *(ushort4v*)&Ts[row][seg * 4] =
            *(const ushort4v*)(vb + (size_t)(t0 + row) * 512 + c0 + seg * 4);
    }
    __syncthreads();
    #pragma unroll
    for (int it = 0; it < 4; ++it) {
        int idx = tid + it * 256;
        int gd = idx >> 4, seg = idx & 15;
        ushort4v y;
        #pragma unroll
        for (int j = 0; j < 4; ++j) y[j] = Ts[seg * 4 + j][gd];
        *(ushort4v*)(vt + (size_t)(c0 + gd) * 4096 + t0 + seg * 4) = y;
    }
}

// ---------------------------------------------------------------------------
// Flash attention v2: Q-frags in regs, K direct from global (L1/L2-hot),
// V^T staged async double-buffered into swizzled LDS, 1 barrier/iter, LPT.
// ---------------------------------------------------------------------------
__global__ __launch_bounds__(256) void attn2(
    const unsigned short* __restrict__ Q, const unsigned short* __restrict__ Kb,
    const unsigned short* __restrict__ Vt, unsigned short* __restrict__ O)
{
    const int qt = 31 - blockIdx.x;   // LPT: biggest blocks first
    const int h  = blockIdx.y;
    const int b  = blockIdx.z;
    const int kvh = h / 7;
    const int tid = threadIdx.x, lane = tid & 63, w = tid >> 6;
    const int quad = lane >> 4, l16 = lane & 15;

    __shared__ unsigned short VsT[2][128 * 64];  // [buf][d][key], XOR-swizzled
    __shared__ unsigned short Ps[64][72];

    // Q fragments in registers (A-layout), held for whole kernel
    bf16x8 aq[4];
    {
        const unsigned short* qp =
            Q + (size_t)(b * 2048 + qt * 64 + w * 16 + l16) * 3584 + h * 128 + quad * 8;
        #pragma unroll
        for (int ks = 0; ks < 4; ++ks) aq[ks] = ld8(qp + ks * 32);
    }

    const unsigned short* vbase = Vt + (size_t)kvh * 128 * 4096 + b * 2048;

    auto stageV = [&](int kt, int buf) {
        #pragma unroll
        for (int p = 0; p < 4; ++p) {
            int c = (w * 4 + p) * 64 + lane;   // chunk 0..1023
            int d = c >> 3, sp = c & 7;
            int slog = sp ^ (d & 7);
            GLL16(vbase + (size_t)d * 4096 + kt * 64 + slog * 8,
                  &VsT[buf][0] + (w * 4 + p) * 512);
        }
    };

    stageV(0, 0);

    floatx4 o[8] = {};
    float mrow[4] = {-1e30f, -1e30f, -1e30f, -1e30f};
    float lrow[4] = {0.f, 0.f, 0.f, 0.f};
    const float scaling = 0.08838834764831845f;   // 1/sqrt(128)

    for (int kt = 0; kt <= qt; ++kt) {
        const int cur = kt & 1;
        __syncthreads();                 // VsT[cur] staged; [cur^1] readers done
        if (kt < qt) stageV(kt + 1, cur ^ 1);

        // ---- S = Q K^T (K B-frags straight from global) ----
        floatx4 s[4] = {};
        const unsigned short* kp =
            Kb + (size_t)(b * 2048 + kt * 64) * 512 + kvh * 128 + quad * 8;
        #pragma unroll
        for (int ks = 0; ks < 4; ++ks) {
            bf16x8 kf[4];
            #pragma unroll
            for (int n4 = 0; n4 < 4; ++n4)
                kf[n4] = ld8(kp + (size_t)(n4 * 16 + l16) * 512 + ks * 32);
            #pragma unroll
            for (int n4 = 0; n4 < 4; ++n4)
                s[n4] = mfma16(aq[ks], kf[n4], s[n4]);
        }

        // ---- online softmax ----
        const bool diag = (kt == qt);
        float pvv[4][4];
        #pragma unroll
        for (int r = 0; r < 4; ++r) {
            int qg = qt * 64 + w * 16 + quad * 4 + r;
            float v0 = s[0][r] * scaling;
            float v1 = s[1][r] * scaling;
            float v2 = s[2][r] * scaling;
            float v3 = s[3][r] * scaling;
            if (diag) {
                int kg = kt * 64 + l16;
                if (kg      > qg) v0 = -1e30f;
                if (kg + 16 > qg) v1 = -1e30f;
                if (kg + 32 > qg) v2 = -1e30f;
                if (kg + 48 > qg) v3 = -1e30f;
            }
            float mx = fmaxf(fmaxf(v0, v1), fmaxf(v2, v3));
            #pragma unroll
            for (int off = 1; off < 16; off <<= 1)
                mx = fmaxf(mx, __shfl_xor(mx, off, 64));
            float mnew  = fmaxf(mrow[r], mx);
            float alpha = __expf(mrow[r] - mnew);
            float p0 = __expf(v0 - mnew);
            float p1 = __expf(v1 - mnew);
            float p2 = __expf(v2 - mnew);
            float p3 = __expf(v3 - mnew);
            float rs = p0 + p1 + p2 + p3;
            #pragma unroll
            for (int off = 1; off < 16; off <<= 1)
                rs += __shfl_xor(rs, off, 64);
            lrow[r] = lrow[r] * alpha + rs;
            mrow[r] = mnew;
            #pragma unroll
            for (int d4 = 0; d4 < 8; ++d4) o[d4][r] *= alpha;
            pvv[r][0] = p0; pvv[r][1] = p1; pvv[r][2] = p2; pvv[r][3] = p3;
        }

        // ---- P to LDS (C-layout), read back A-layout (same wave only) ----
        #pragma unroll
        for (int n4 = 0; n4 < 4; ++n4)
            #pragma unroll
            for (int r = 0; r < 4; ++r)
                Ps[w * 16 + quad * 4 + r][n4 * 16 + l16] = f2bf(pvv[r][n4]);

        // ---- O += P V (B-frags from swizzled VsT) ----
        #pragma unroll
        for (int ks2 = 0; ks2 < 2; ++ks2) {
            bf16x8 ap = ld8(&Ps[w * 16 + l16][ks2 * 32 + quad * 8]);
            #pragma unroll
            for (int d4 = 0; d4 < 8; ++d4) {
                int d = d4 * 16 + l16;
                int sp = (ks2 * 4 + quad) ^ (d & 7);
                bf16x8 bv = ld8(&VsT[cur][d * 64 + sp * 8]);
                o[d4] = mfma16(ap, bv, o[d4]);
            }
        }
    }

    #pragma unroll
    for (int d4 = 0; d4 < 8; ++d4) {
        int col = h * 128 + d4 * 16 + l16;
        #pragma unroll
        for (int r = 0; r < 4; ++r) {
            int row = b * 2048 + qt * 64 + w * 16 + quad * 4 + r;
            O[(size_t)row * 3584 + col] = f2bf(o[d4][r] / lrow[r]);
        }
    }
}

// ---------------------------------------------------------------------------
extern "C" void kernel_launch(void* const* d_in, const int* in_sizes, int n_in,
                              void* d_out, int out_size, void* d_ws, size_t ws_size,
                              hipStream_t stream)
{
    (void)in_sizes; (void)n_in; (void)out_size;
    const float* hs   = (const float*)d_in[0];
    const float* cosp = (const float*)d_in[1];
    const float* sinp = (const float*)d_in[2];
    const float* Wq   = (const float*)d_in[3];
    const float* bq   = (const float*)d_in[4];
    const float* Wk   = (const float*)d_in[5];
    const float* bk   = (const float*)d_in[6];
    const float* Wv   = (const float*)d_in[7];
    const float* bv   = (const float*)d_in[8];
    const float* Wo   = (const float*)d_in[9];
    float* out = (float*)d_out;

    const size_t NHS = 14680064;   // 4096*3584
    const size_t NWQ = 12845056;   // 3584*3584
    const size_t NWKV = 1835008;   // 512*3584
    const size_t NWO = 12845056;
    const size_t NQ  = 14680064;
    const size_t NKV = 2097152;    // 4096*512

    const size_t need = 2 * (NHS + NQ + NQ + 3 * NKV + NWQ + 2 * NWKV + NWO);
    dim3 blk(256);

    if (ws_size >= need) {
        unsigned short* hb  = (unsigned short*)d_ws;
        unsigned short* qb  = hb + NHS;
        unsigned short* ab  = qb + NQ;
        unsigned short* kb  = ab + NQ;
        unsigned short* vb  = kb + NKV;
        unsigned short* vt  = vb + NKV;
        unsigned short* Wqb = vt + NKV;
        unsigned short* Wkb = Wqb + NWQ;
        unsigned short* Wvb = Wkb + NWKV;
        unsigned short* Wob = Wvb + NWKV;

        convert5<<<dim3(1024), blk, 0, stream>>>(
            hs, Wq, Wk, Wv, Wo, hb, Wqb, Wkb, Wvb, Wob,
            (int)(NHS / 4), (int)(NWQ / 4), (int)(NWKV / 4), (int)(NWKV / 4), (int)(NWO / 4));

        gemm_bb<true, true><<<dim3(32, 28), blk, 0, stream>>>(hb, Wqb, bq, qb, 3584, 3584);
        gemm_bb<true, true><<<dim3(32, 4),  blk, 0, stream>>>(hb, Wkb, bk, kb, 3584, 512);
        gemm_bb<true, true><<<dim3(32, 4),  blk, 0, stream>>>(hb, Wvb, bv, vb, 3584, 512);
        rope2<<<dim3(4096), blk, 0, stream>>>(qb, kb, cosp, sinp);
        transpose_v<<<dim3(64, 8), blk, 0, stream>>>(vb, vt);
        attn2<<<dim3(32, 28, 2), blk, 0, stream>>>(qb, kb, vt, ab);
        gemm_bb<false, false><<<dim3(32, 28), blk, 0, stream>>>(ab, Wob, nullptr, out, 3584, 3584);
    } else {
        unsigned short* qb = (unsigned short*)d_ws;
        unsigned short* kb = qb + NQ;
        unsigned short* vb = kb + NKV;
        unsigned short* vt = vb + NKV;
        unsigned short* ab = vt + NKV;

        gemm_nt<false, true, true><<<dim3(32, 28), blk, 0, stream>>>(hs, Wq, bq, qb, 3584, 3584);
        gemm_nt<false, true, true><<<dim3(32, 4),  blk, 0, stream>>>(hs, Wk, bk, kb, 3584, 512);
        gemm_nt<false, true, true><<<dim3(32, 4),  blk, 0, stream>>>(hs, Wv, bv, vb, 3584, 512);
        rope2<<<dim3(4096), blk, 0, stream>>>(qb, kb, cosp, sinp);
        transpose_v<<<dim3(64, 8), blk, 0, stream>>>(vb, vt);
        attn2<<<dim3(32, 28, 2), blk, 0, stream>>>(qb, kb, vt, ab);
        gemm_nt<true, false, false><<<dim3(32, 28), blk, 0, stream>>>(ab, Wo, nullptr, out, 3584, 3584);
    }
}